// Round 16
// baseline (44.824 us; speedup 1.0000x reference)
//
#include <hip/hip_runtime.h>
#include <hip/hip_bf16.h>

#define HW 65536

typedef short short8 __attribute__((ext_vector_type(8)));
typedef float f32x4 __attribute__((ext_vector_type(4)));

__device__ __forceinline__ unsigned short f2bf(float x) {
    return __builtin_bit_cast(unsigned short, __float2bfloat16(x));
}
__device__ __forceinline__ f32x4 mfma16(short8 a, short8 b, f32x4 c) {
    return __builtin_amdgcn_mfma_f32_16x16x32_bf16(a, b, c, 0, 0, 0);
}
__device__ __forceinline__ short8 packw8(const float* w) {
    const float4 a = *(const float4*)w;
    const float4 b = *(const float4*)(w + 4);
    uint4 u;
    u.x = f2bf(a.x) | ((unsigned)f2bf(a.y) << 16);
    u.y = f2bf(a.z) | ((unsigned)f2bf(a.w) << 16);
    u.z = f2bf(b.x) | ((unsigned)f2bf(b.y) << 16);
    u.w = f2bf(b.z) | ((unsigned)f2bf(b.w) << 16);
    return __builtin_bit_cast(short8, u);
}

// ---------------- residual conv kernel (always runs, writes all of out) ----
// Clean occupancy experiment (r14 was confounded by nt-stores): r13/r15
// access pattern exactly — LDS-staged transpose, full-line coalesced loads,
// NORMAL stores — but half-row blocks: 16 KB LDS -> 8 blocks/CU = 32/32
// wave slots. tid&127 = px, tid>>7 = channel half.
__global__ __launch_bounds__(256, 8) void res_kernel(
    const float* __restrict__ xg_l, const float* __restrict__ xg_r,
    const float* __restrict__ wlres, const float* __restrict__ blres,
    const float* __restrict__ wrres, const float* __restrict__ brres,
    float* __restrict__ out)
{
    __shared__ __align__(16) uint4 X16[1024];   // 16 KB, swizzled px-major bf16

    const int gx = blockIdx.x;
    const int bh = gx >> 1;                     // (b*256 + h)
    const int ph = (gx & 1) * 128;              // px base of this half-row
    const int side = blockIdx.y;
    const int b = bh >> 8, h = bh & 255;
    const int tid = threadIdx.x;
    const int wv = tid >> 6, lane = tid & 63;
    const int g = lane >> 4, lr = lane & 15;
    const int px = tid & 127, chh = tid >> 7;   // 2 threads per px

    const float* xg = side ? xg_r : xg_l;
    const float* W  = side ? wrres : wlres;
    const float* Bz = side ? brres : blres;

    const size_t obase = (size_t)b * 64 * HW + (size_t)h * 256;

    // ---- stage X: this thread's 32 channels of pixel (ph+px) ----
    const float* xp = xg + obase + ph + px;
#pragma unroll
    for (int cb = 0; cb < 4; ++cb) {
        float v[8];
#pragma unroll
        for (int k = 0; k < 8; ++k) v[k] = xp[(size_t)(chh * 32 + cb * 8 + k) * HW];
        uint4 u;
        u.x = f2bf(v[0]) | ((unsigned)f2bf(v[1]) << 16);
        u.y = f2bf(v[2]) | ((unsigned)f2bf(v[3]) << 16);
        u.z = f2bf(v[4]) | ((unsigned)f2bf(v[5]) << 16);
        u.w = f2bf(v[6]) | ((unsigned)f2bf(v[7]) << 16);
        X16[px * 8 + ((chh * 4 + cb) ^ (px & 7))] = u;
    }

    // ---- weight fragments (in-register f32->bf16), bias ----
    short8 af[2][2];
    f32x4 bz[2];
#pragma unroll
    for (int ot = 0; ot < 2; ++ot) {
        af[ot][0] = packw8(&W[(ot * 16 + lr) * 64 + 8 * g]);
        af[ot][1] = packw8(&W[(ot * 16 + lr) * 64 + 32 + 8 * g]);
        bz[ot] = *(const f32x4*)&Bz[ot * 16 + 4 * g];
    }
    __syncthreads();

    // ---- 2 px-tiles per wave: LDS fragments, MFMA, normal store ----
    float* outp = out + obase + ph + (size_t)(side * 32) * HW;
#pragma unroll
    for (int i = 0; i < 2; ++i) {
        const int p = (wv * 2 + i) * 16 + lr;
        const short8 xb0 = __builtin_bit_cast(short8, X16[p * 8 + (g ^ (p & 7))]);
        const short8 xb1 = __builtin_bit_cast(short8, X16[p * 8 + ((4 + g) ^ (p & 7))]);
#pragma unroll
        for (int ot = 0; ot < 2; ++ot) {
            f32x4 acc = {0.f, 0.f, 0.f, 0.f};
            acc = mfma16(af[ot][0], xb0, acc);
            acc = mfma16(af[ot][1], xb1, acc);
            float* op = outp + p + (size_t)(ot * 16 + 4 * g) * HW;
#pragma unroll
            for (int r = 0; r < 4; ++r) op[(size_t)r * HW] = acc[r] + bz[ot][r];
        }
    }
}

// ---------------- weight prep (4 blocks) — attention weights only ----------
// wpack (bf16): [0]Wql'(64x64, W*lnw) [4096]Wqr [8192]Wvl [10240]Wvr
// st (f32): s[64], t[64]
__global__ __launch_bounds__(64) void prep_kernel(
    const float* __restrict__ wl1, const float* __restrict__ bl1,
    const float* __restrict__ wr1,
    const float* __restrict__ wl2, const float* __restrict__ wr2,
    const float* __restrict__ lnw, const float* __restrict__ lnb,
    __hip_bfloat16* __restrict__ wpack, float* __restrict__ st)
{
    const int m = blockIdx.x;
    const int o = threadIdx.x;
    if (m == 0) {
        float s = 0.f, t = 0.f;
        for (int c = 0; c < 64; ++c) {
            __hip_bfloat16 wb = __float2bfloat16(wl1[o*64+c] * lnw[c]);
            wpack[o*64+c] = wb;
            s += __bfloat162float(wb);
            t += wl1[o*64+c] * lnb[c];
        }
        st[o] = s;
        st[64+o] = t + bl1[o];
    } else if (m == 1) {
        for (int c = 0; c < 64; ++c) wpack[4096 + o*64+c] = __float2bfloat16(wr1[o*64+c]);
    } else if (m == 2) {
        if (o < 32) for (int c = 0; c < 64; ++c)
            wpack[8192 + o*64+c] = __float2bfloat16(wl2[o*64+c]);
    } else {
        if (o < 32) for (int c = 0; c < 64; ++c)
            wpack[10240 + o*64+c] = __float2bfloat16(wr2[o*64+c]);
    }
}

// ---------------- gated attention kernel ----------------
// Early-exits (before any x traffic) when both beta and gamma are all-zero:
// out = res + coef*attn, so zero coef kills the whole attention path exactly.
// For nonzero gates: full LN + q/v projection + bidirectional attention, += out.
#define QL_OFF 0
#define QR_OFF 32768
#define VL_OFF 65536
#define VR_OFF 81920
#define XP_OFF 98304
#define AUX_OFF 131072
#define SMEM_BYTES (131072 + 7680)

__global__ __launch_bounds__(512, 2) void attn_kernel(
    const float* __restrict__ xg_l, const float* __restrict__ xg_r,
    const __hip_bfloat16* __restrict__ wpack, const float* __restrict__ st,
    const float* __restrict__ bqr_g, const float* __restrict__ bl2,
    const float* __restrict__ br2, const float* __restrict__ beta,
    const float* __restrict__ gamma, float* __restrict__ out)
{
    __shared__ __align__(16) unsigned char smem[SMEM_BYTES];
    __shared__ int sNeed[2];

    const int tid = threadIdx.x;
    float* coefA = (float*)(smem + AUX_OFF + 3328);

    if (tid < 64) {   // exactly wave 0
        const float cf = tid < 32 ? beta[tid] : gamma[tid - 32];
        coefA[tid] = cf;
        unsigned long long m = __ballot(cf != 0.f);
        if (tid == 0) {
            sNeed[0] = (unsigned)(m & 0xffffffffull) ? 1 : 0;  // beta  -> dir 0
            sNeed[1] = (unsigned)(m >> 32)           ? 1 : 0;  // gamma -> dir 1
        }
    }
    __syncthreads();
    const bool needL = sNeed[0] != 0;
    const bool needR = sNeed[1] != 0;
    if (!(needL || needR)) return;   // gates all zero: attention contributes 0

    const int bh = blockIdx.x;
    const int b = bh >> 8, h = bh & 255;
    const int wv = tid >> 6, lane = tid & 63;
    const int g = lane >> 4, lr = lane & 15;
    const int px = tid & 255, half = tid >> 8;

    float* aArr  = (float*)(smem + AUX_OFF);          // rstd per px (1K)
    float* bbArr = (float*)(smem + AUX_OFF + 1024);   // -rstd*mu per px (1K)
    float* sArr  = (float*)(smem + AUX_OFF + 2048);
    float* tArr  = (float*)(smem + AUX_OFF + 2304);
    float* bqrA  = (float*)(smem + AUX_OFF + 2560);
    float* bvA   = (float*)(smem + AUX_OFF + 2816);
    float* pS    = (float*)(smem + AUX_OFF + 3584);   // 2K
    float* pQ    = (float*)(smem + AUX_OFF + 5632);   // 2K

    const size_t obase = (size_t)b * 64 * HW + (size_t)h * 256;
    const size_t xbase = obase + px;

    // ---- each thread loads 32 channels of both x rows (coalesced) ----
    float xl[32], xr_[32];
#pragma unroll
    for (int c = 0; c < 32; ++c) xl[c] = xg_l[xbase + (size_t)(half*32 + c) * HW];
#pragma unroll
    for (int c = 0; c < 32; ++c) xr_[c] = xg_r[xbase + (size_t)(half*32 + c) * HW];

    if (tid < 64) {
        sArr[tid] = st[tid];
        tArr[tid] = st[64 + tid];
        bqrA[tid] = bqr_g[tid];
        bvA[tid]  = tid < 32 ? bl2[tid] : br2[tid - 32];
    }

    // ---- LN partial stats for left row ----
    {
        float s = 0.f, q = 0.f;
#pragma unroll
        for (int c = 0; c < 32; ++c) { s += xl[c]; q = fmaf(xl[c], xl[c], q); }
        pS[half*256 + px] = s;
        pQ[half*256 + px] = q;
    }

    // ---- stage X_left px-major bf16 swizzled ----
    uint4* X16 = (uint4*)(smem + XP_OFF);
#pragma unroll
    for (int cb = 0; cb < 4; ++cb) {
        uint4 u;
        u.x = f2bf(xl[cb*8+0]) | ((unsigned)f2bf(xl[cb*8+1]) << 16);
        u.y = f2bf(xl[cb*8+2]) | ((unsigned)f2bf(xl[cb*8+3]) << 16);
        u.z = f2bf(xl[cb*8+4]) | ((unsigned)f2bf(xl[cb*8+5]) << 16);
        u.w = f2bf(xl[cb*8+6]) | ((unsigned)f2bf(xl[cb*8+7]) << 16);
        X16[px*8 + ((half*4 + cb) ^ (px & 7))] = u;
    }
    __syncthreads();
    if (half == 0) {
        float s = pS[px] + pS[256 + px];
        float q = pQ[px] + pQ[256 + px];
        float mu = s * (1.f / 64.f);
        float var = q * (1.f / 64.f) - mu * mu;
        float rstd = rsqrtf(var + 1e-6f);
        aArr[px] = rstd;
        bbArr[px] = -rstd * mu;
    }
    __syncthreads();

    const uint4* W16 = (const uint4*)wpack;

    // proj one side (q always; v gated) over this wave's 2 px-tiles
    auto proj_side = [&](int wq, int wvv, unsigned char* qdst,
                         unsigned char* vdst, int chbase, bool ln, bool doV) {
        short8 bfr0[2], bfr1[2];
#pragma unroll
        for (int i = 0; i < 2; ++i) {
            int p = (wv*2 + i)*16 + lr;
            bfr0[i] = __builtin_bit_cast(short8, X16[p*8 + (g ^ (p&7))]);
            bfr1[i] = __builtin_bit_cast(short8, X16[p*8 + ((4+g) ^ (p&7))]);
        }
        // ---- q: D[ch][px] ----
#pragma unroll
        for (int ot = 0; ot < 4; ++ot) {
            const int out0 = ot * 16;
            short8 af0 = __builtin_bit_cast(short8, W16[wq + (out0+lr)*8 + g]);
            short8 af1 = __builtin_bit_cast(short8, W16[wq + (out0+lr)*8 + 4 + g]);
            const int ch0 = out0 + 4*g;
            f32x4 c1 = *(const f32x4*)&(ln ? sArr : bqrA)[ch0];
            f32x4 c2 = ln ? *(const f32x4*)&tArr[ch0] : (f32x4){0.f,0.f,0.f,0.f};
#pragma unroll
            for (int i = 0; i < 2; ++i) {
                f32x4 acc = {0.f,0.f,0.f,0.f};
                acc = mfma16(af0, bfr0[i], acc);
                acc = mfma16(af1, bfr1[i], acc);
                const int p = (wv*2+i)*16 + lr;
                float q0,q1,q2,q3;
                if (ln) {
                    const float a_ = aArr[p], b_ = bbArr[p];
                    q0 = fmaf(a_, acc[0], fmaf(b_, c1[0], c2[0]));
                    q1 = fmaf(a_, acc[1], fmaf(b_, c1[1], c2[1]));
                    q2 = fmaf(a_, acc[2], fmaf(b_, c1[2], c2[2]));
                    q3 = fmaf(a_, acc[3], fmaf(b_, c1[3], c2[3]));
                } else {
                    q0 = acc[0]+c1[0]; q1 = acc[1]+c1[1];
                    q2 = acc[2]+c1[2]; q3 = acc[3]+c1[3];
                }
                unsigned lo = f2bf(q0) | ((unsigned)f2bf(q1) << 16);
                unsigned hi = f2bf(q2) | ((unsigned)f2bf(q3) << 16);
                *(uint2*)(qdst + p*128 + (((ch0>>3) ^ (p&7))*16) + (ch0&7)*2)
                    = make_uint2(lo, hi);
            }
        }
        // ---- v: swapped operands -> D[px][ch], 8B store ----
        if (doV) {
#pragma unroll
            for (int ot = 0; ot < 2; ++ot) {
                const int out0 = ot * 16;
                short8 af0 = __builtin_bit_cast(short8, W16[wvv + (out0+lr)*8 + g]);
                short8 af1 = __builtin_bit_cast(short8, W16[wvv + (out0+lr)*8 + 4 + g]);
                const int ch = out0 + lr;
                const float bv = bvA[chbase + ch];
#pragma unroll
                for (int i = 0; i < 2; ++i) {
                    f32x4 acc = {0.f,0.f,0.f,0.f};
                    acc = mfma16(bfr0[i], af0, acc);
                    acc = mfma16(bfr1[i], af1, acc);
                    unsigned lo = f2bf(acc[0]+bv) | ((unsigned)f2bf(acc[1]+bv) << 16);
                    unsigned hi = f2bf(acc[2]+bv) | ((unsigned)f2bf(acc[3]+bv) << 16);
                    const int vb = (wv*2+i)*2 + (g>>1);
                    *(uint2*)(vdst + ch*512 + ((vb ^ (ch&7))*16) + (g&1)*8)
                        = make_uint2(lo, hi);
                }
            }
        }
    };

    // v_l (VL) feeds dir1 (gamma); v_r (VR) feeds dir0 (beta)
    proj_side(0, 1024, smem + QL_OFF, smem + VL_OFF, 0, true, needR);
    __syncthreads();

    // ---- stage X_right ----
#pragma unroll
    for (int cb = 0; cb < 4; ++cb) {
        uint4 u;
        u.x = f2bf(xr_[cb*8+0]) | ((unsigned)f2bf(xr_[cb*8+1]) << 16);
        u.y = f2bf(xr_[cb*8+2]) | ((unsigned)f2bf(xr_[cb*8+3]) << 16);
        u.z = f2bf(xr_[cb*8+4]) | ((unsigned)f2bf(xr_[cb*8+5]) << 16);
        u.w = f2bf(xr_[cb*8+6]) | ((unsigned)f2bf(xr_[cb*8+7]) << 16);
        X16[px*8 + ((half*4 + cb) ^ (px & 7))] = u;
    }
    __syncthreads();

    proj_side(512, 1280, smem + QR_OFF, smem + VR_OFF, 32, false, needL);
    __syncthreads();   // all q/v in LDS; X region becomes P

    // ------- attention: waves 0-3 dir0, waves 4-7 dir1; 4 chunks each -------
    const int dir = wv >> 2, wsub = wv & 3;
    if (dir ? needR : needL) {
        unsigned char* Pw = smem + XP_OFF + wv * 4096;
        const float cs = 0.125f * 1.44269504088896f;   // scale * log2(e)

        const uint4* Q16 = (const uint4*)(smem + (dir ? QR_OFF : QL_OFF));
        const uint4* K16 = (const uint4*)(smem + (dir ? QL_OFF : QR_OFF));
        const uint4* V16 = (const uint4*)(smem + (dir ? VL_OFF : VR_OFF));
        const float* coef = coefA + dir * 32;

        for (int c = 0; c < 4; ++c) {
            const int row0 = c * 64 + wsub * 16;
            const int qpx = row0 + lr;
            short8 qf0 = __builtin_bit_cast(short8, Q16[qpx*8 + (g ^ (qpx&7))]);
            short8 qf1 = __builtin_bit_cast(short8, Q16[qpx*8 + ((4+g) ^ (qpx&7))]);

            f32x4 sacc[16];
#pragma unroll
            for (int t = 0; t < 16; ++t) sacc[t] = (f32x4){0.f,0.f,0.f,0.f};
            __builtin_amdgcn_s_setprio(1);
#pragma unroll
            for (int t = 0; t < 16; ++t) {
                const int key = t * 16 + lr;
                const int sw = key & 7;
                short8 a0 = __builtin_bit_cast(short8, K16[key*8 + (g ^ sw)]);
                short8 a1 = __builtin_bit_cast(short8, K16[key*8 + ((4+g) ^ sw)]);
                sacc[t] = mfma16(a0, qf0, sacc[t]);
                sacc[t] = mfma16(a1, qf1, sacc[t]);
            }
            __builtin_amdgcn_s_setprio(0);
            float mx = -3.0e38f;
#pragma unroll
            for (int t = 0; t < 16; ++t)
                mx = fmaxf(mx, fmaxf(fmaxf(sacc[t][0], sacc[t][1]),
                                     fmaxf(sacc[t][2], sacc[t][3])));
            mx = fmaxf(mx, __shfl_xor(mx, 16));
            mx = fmaxf(mx, __shfl_xor(mx, 32));

            float lsum = 0.f;
            f32x4 o0 = (f32x4){0.f,0.f,0.f,0.f};
            f32x4 o1 = (f32x4){0.f,0.f,0.f,0.f};
#pragma unroll
            for (int hh = 0; hh < 2; ++hh) {
#pragma unroll
                for (int t8 = 0; t8 < 8; ++t8) {
                    const int t16 = hh * 8 + t8;
                    float p0 = exp2f((sacc[t16][0] - mx) * cs);
                    float p1 = exp2f((sacc[t16][1] - mx) * cs);
                    float p2 = exp2f((sacc[t16][2] - mx) * cs);
                    float p3 = exp2f((sacc[t16][3] - mx) * cs);
                    lsum += (p0 + p1) + (p2 + p3);
                    unsigned lo = f2bf(p0) | ((unsigned)f2bf(p1) << 16);
                    unsigned hi = f2bf(p2) | ((unsigned)f2bf(p3) << 16);
                    int pb = (2*t8 + (g >> 1)) ^ (lr & 7);
                    *(uint2*)(Pw + lr*256 + pb*16 + (g & 1)*8) = make_uint2(lo, hi);
                }
#pragma unroll
                for (int t = 0; t < 4; ++t) {
                    const int pb = 4*t + g;
                    const int vb = 16*hh + 4*t + g;
                    short8 pa = __builtin_bit_cast(short8,
                                *(const uint4*)(Pw + lr*256 + ((pb ^ (lr&7))*16)));
                    short8 v0 = __builtin_bit_cast(short8, V16[lr*32 + (vb ^ (lr&7))]);
                    short8 v1 = __builtin_bit_cast(short8, V16[(16+lr)*32 + (vb ^ (lr&7))]);
                    o0 = mfma16(pa, v0, o0);
                    o1 = mfma16(pa, v1, o1);
                }
            }
            lsum += __shfl_xor(lsum, 16);
            lsum += __shfl_xor(lsum, 32);
            const float inv = 1.f / lsum;

            float* Ot = (float*)Pw;
#pragma unroll
            for (int r = 0; r < 4; ++r) Ot[lr*17 + (g*4 + r)] = o0[r];
#pragma unroll
            for (int r = 0; r < 4; ++r) Ot[(16+lr)*17 + (g*4 + r)] = o1[r];

            float* outp = out + obase + (size_t)(dir*32) * HW + row0 + lr;
#pragma unroll
            for (int it = 0; it < 8; ++it) {
                const int ch = it*4 + g;
                outp[(size_t)ch * HW] += Ot[ch*17 + lr] * inv * coef[ch];
            }
        }
    }
}

extern "C" void kernel_launch(void* const* d_in, const int* in_sizes, int n_in,
                              void* d_out, int out_size, void* d_ws, size_t ws_size,
                              hipStream_t stream) {
    (void)in_sizes; (void)n_in; (void)out_size; (void)ws_size;
    const float* xr    = (const float*)d_in[0];
    const float* xh    = (const float*)d_in[1];
    const float* lnw   = (const float*)d_in[2];
    const float* lnb   = (const float*)d_in[3];
    const float* wl1   = (const float*)d_in[4];
    const float* bl1   = (const float*)d_in[5];
    const float* wr1   = (const float*)d_in[6];
    const float* br1   = (const float*)d_in[7];
    const float* wl2   = (const float*)d_in[8];
    const float* bl2   = (const float*)d_in[9];
    const float* wr2   = (const float*)d_in[10];
    const float* br2   = (const float*)d_in[11];
    const float* wlres = (const float*)d_in[12];
    const float* blres = (const float*)d_in[13];
    const float* wrres = (const float*)d_in[14];
    const float* brres = (const float*)d_in[15];
    const float* beta  = (const float*)d_in[16];
    const float* gamma = (const float*)d_in[17];
    float* out = (float*)d_out;

    __hip_bfloat16* wpack = (__hip_bfloat16*)d_ws;
    float* st = (float*)((unsigned char*)d_ws + 32768);

    res_kernel<<<dim3(2048, 2), dim3(256), 0, stream>>>(
        xr, xh, wlres, blres, wrres, brres, out);
    prep_kernel<<<dim3(4), dim3(64), 0, stream>>>(
        wl1, bl1, wr1, wl2, wr2, lnw, lnb, wpack, st);
    attn_kernel<<<dim3(1024), dim3(512), 0, stream>>>(
        xr, xh, wpack, st, br1, bl2, br2, beta, gamma, out);
}

// Round 17
// 42.443 us; speedup vs baseline: 1.0561x; 1.0561x over previous
//
#include <hip/hip_runtime.h>
#include <hip/hip_bf16.h>

#define HW 65536

typedef short short8 __attribute__((ext_vector_type(8)));
typedef float f32x4 __attribute__((ext_vector_type(4)));

__device__ __forceinline__ unsigned short f2bf(float x) {
    return __builtin_bit_cast(unsigned short, __float2bfloat16(x));
}
__device__ __forceinline__ f32x4 mfma16(short8 a, short8 b, f32x4 c) {
    return __builtin_amdgcn_mfma_f32_16x16x32_bf16(a, b, c, 0, 0, 0);
}
__device__ __forceinline__ short8 packw8(const float* w) {
    const float4 a = *(const float4*)w;
    const float4 b = *(const float4*)(w + 4);
    uint4 u;
    u.x = f2bf(a.x) | ((unsigned)f2bf(a.y) << 16);
    u.y = f2bf(a.z) | ((unsigned)f2bf(a.w) << 16);
    u.z = f2bf(b.x) | ((unsigned)f2bf(b.y) << 16);
    u.w = f2bf(b.z) | ((unsigned)f2bf(b.w) << 16);
    return __builtin_bit_cast(short8, u);
}

// ---------------- residual conv kernel (always runs, writes all of out) ----
// FINAL (r13/r15 empirical best): LDS-staged transpose, tid = px ->
// full-line coalesced loads, one (row, side) per 256-thread block,
// 32 KB LDS -> 5 blocks/CU, single barrier, normal stores.
// Counter evidence across r11-r16: traffic within 1% of algorithmic minimum
// (FETCH 65.6 MB + WRITE 66 MB), bank conflicts 0, compute negligible
// (MFMA 1.2%, VALU ~8%). Alternatives refuted: zero-LDS (r12: 2.3x FETCH),
// nt-stores (r14: +20% WRITE), occupancy doubling (r16: flat at 64% occ).
// ~5.4 TB/s combined L3+HBM service -> memory-bound at ~85% of ceiling.
__global__ __launch_bounds__(256, 5) void res_kernel(
    const float* __restrict__ xg_l, const float* __restrict__ xg_r,
    const float* __restrict__ wlres, const float* __restrict__ blres,
    const float* __restrict__ wrres, const float* __restrict__ brres,
    float* __restrict__ out)
{
    __shared__ __align__(16) uint4 X16[2048];   // 32 KB, swizzled px-major bf16

    const int bh = blockIdx.x;
    const int side = blockIdx.y;
    const int b = bh >> 8, h = bh & 255;
    const int tid = threadIdx.x;                // = px
    const int wv = tid >> 6, lane = tid & 63;
    const int g = lane >> 4, lr = lane & 15;

    const float* xg = side ? xg_r : xg_l;
    const float* W  = side ? wrres : wlres;
    const float* Bz = side ? brres : blres;

    const size_t obase = (size_t)b * 64 * HW + (size_t)h * 256;

    // ---- stage X: thread = px, 64 channels, pack 8 at a time ----
    const float* xp = xg + obase + tid;
#pragma unroll
    for (int cb = 0; cb < 8; ++cb) {
        float v[8];
#pragma unroll
        for (int k = 0; k < 8; ++k) v[k] = xp[(size_t)(cb * 8 + k) * HW];
        uint4 u;
        u.x = f2bf(v[0]) | ((unsigned)f2bf(v[1]) << 16);
        u.y = f2bf(v[2]) | ((unsigned)f2bf(v[3]) << 16);
        u.z = f2bf(v[4]) | ((unsigned)f2bf(v[5]) << 16);
        u.w = f2bf(v[6]) | ((unsigned)f2bf(v[7]) << 16);
        X16[tid * 8 + (cb ^ (tid & 7))] = u;
    }

    // ---- weight fragments (in-register f32->bf16), bias ----
    short8 af[2][2];
    f32x4 bz[2];
#pragma unroll
    for (int ot = 0; ot < 2; ++ot) {
        af[ot][0] = packw8(&W[(ot * 16 + lr) * 64 + 8 * g]);
        af[ot][1] = packw8(&W[(ot * 16 + lr) * 64 + 32 + 8 * g]);
        bz[ot] = *(const f32x4*)&Bz[ot * 16 + 4 * g];
    }
    __syncthreads();

    // ---- 4 px-tiles per wave: LDS fragments, MFMA, store ----
    float* outp = out + obase + (size_t)(side * 32) * HW;
#pragma unroll
    for (int i = 0; i < 4; ++i) {
        const int p = (wv * 4 + i) * 16 + lr;
        const short8 xb0 = __builtin_bit_cast(short8, X16[p * 8 + (g ^ (p & 7))]);
        const short8 xb1 = __builtin_bit_cast(short8, X16[p * 8 + ((4 + g) ^ (p & 7))]);
#pragma unroll
        for (int ot = 0; ot < 2; ++ot) {
            f32x4 acc = {0.f, 0.f, 0.f, 0.f};
            acc = mfma16(af[ot][0], xb0, acc);
            acc = mfma16(af[ot][1], xb1, acc);
            float* op = outp + p + (size_t)(ot * 16 + 4 * g) * HW;
#pragma unroll
            for (int r = 0; r < 4; ++r) op[(size_t)r * HW] = acc[r] + bz[ot][r];
        }
    }
}

// ---------------- weight prep (4 blocks) — attention weights only ----------
// wpack (bf16): [0]Wql'(64x64, W*lnw) [4096]Wqr [8192]Wvl [10240]Wvr
// st (f32): s[64], t[64]
__global__ __launch_bounds__(64) void prep_kernel(
    const float* __restrict__ wl1, const float* __restrict__ bl1,
    const float* __restrict__ wr1,
    const float* __restrict__ wl2, const float* __restrict__ wr2,
    const float* __restrict__ lnw, const float* __restrict__ lnb,
    __hip_bfloat16* __restrict__ wpack, float* __restrict__ st)
{
    const int m = blockIdx.x;
    const int o = threadIdx.x;
    if (m == 0) {
        float s = 0.f, t = 0.f;
        for (int c = 0; c < 64; ++c) {
            __hip_bfloat16 wb = __float2bfloat16(wl1[o*64+c] * lnw[c]);
            wpack[o*64+c] = wb;
            s += __bfloat162float(wb);
            t += wl1[o*64+c] * lnb[c];
        }
        st[o] = s;
        st[64+o] = t + bl1[o];
    } else if (m == 1) {
        for (int c = 0; c < 64; ++c) wpack[4096 + o*64+c] = __float2bfloat16(wr1[o*64+c]);
    } else if (m == 2) {
        if (o < 32) for (int c = 0; c < 64; ++c)
            wpack[8192 + o*64+c] = __float2bfloat16(wl2[o*64+c]);
    } else {
        if (o < 32) for (int c = 0; c < 64; ++c)
            wpack[10240 + o*64+c] = __float2bfloat16(wr2[o*64+c]);
    }
}

// ---------------- gated attention kernel ----------------
// Early-exits (before any x traffic) when both beta and gamma are all-zero:
// out = res + coef*attn, so zero coef kills the whole attention path exactly.
// For nonzero gates: full LN + q/v projection + bidirectional attention, += out.
#define QL_OFF 0
#define QR_OFF 32768
#define VL_OFF 65536
#define VR_OFF 81920
#define XP_OFF 98304
#define AUX_OFF 131072
#define SMEM_BYTES (131072 + 7680)

__global__ __launch_bounds__(512, 2) void attn_kernel(
    const float* __restrict__ xg_l, const float* __restrict__ xg_r,
    const __hip_bfloat16* __restrict__ wpack, const float* __restrict__ st,
    const float* __restrict__ bqr_g, const float* __restrict__ bl2,
    const float* __restrict__ br2, const float* __restrict__ beta,
    const float* __restrict__ gamma, float* __restrict__ out)
{
    __shared__ __align__(16) unsigned char smem[SMEM_BYTES];
    __shared__ int sNeed[2];

    const int tid = threadIdx.x;
    float* coefA = (float*)(smem + AUX_OFF + 3328);

    if (tid < 64) {   // exactly wave 0
        const float cf = tid < 32 ? beta[tid] : gamma[tid - 32];
        coefA[tid] = cf;
        unsigned long long m = __ballot(cf != 0.f);
        if (tid == 0) {
            sNeed[0] = (unsigned)(m & 0xffffffffull) ? 1 : 0;  // beta  -> dir 0
            sNeed[1] = (unsigned)(m >> 32)           ? 1 : 0;  // gamma -> dir 1
        }
    }
    __syncthreads();
    const bool needL = sNeed[0] != 0;
    const bool needR = sNeed[1] != 0;
    if (!(needL || needR)) return;   // gates all zero: attention contributes 0

    const int bh = blockIdx.x;
    const int b = bh >> 8, h = bh & 255;
    const int wv = tid >> 6, lane = tid & 63;
    const int g = lane >> 4, lr = lane & 15;
    const int px = tid & 255, half = tid >> 8;

    float* aArr  = (float*)(smem + AUX_OFF);          // rstd per px (1K)
    float* bbArr = (float*)(smem + AUX_OFF + 1024);   // -rstd*mu per px (1K)
    float* sArr  = (float*)(smem + AUX_OFF + 2048);
    float* tArr  = (float*)(smem + AUX_OFF + 2304);
    float* bqrA  = (float*)(smem + AUX_OFF + 2560);
    float* bvA   = (float*)(smem + AUX_OFF + 2816);
    float* pS    = (float*)(smem + AUX_OFF + 3584);   // 2K
    float* pQ    = (float*)(smem + AUX_OFF + 5632);   // 2K

    const size_t obase = (size_t)b * 64 * HW + (size_t)h * 256;
    const size_t xbase = obase + px;

    // ---- each thread loads 32 channels of both x rows (coalesced) ----
    float xl[32], xr_[32];
#pragma unroll
    for (int c = 0; c < 32; ++c) xl[c] = xg_l[xbase + (size_t)(half*32 + c) * HW];
#pragma unroll
    for (int c = 0; c < 32; ++c) xr_[c] = xg_r[xbase + (size_t)(half*32 + c) * HW];

    if (tid < 64) {
        sArr[tid] = st[tid];
        tArr[tid] = st[64 + tid];
        bqrA[tid] = bqr_g[tid];
        bvA[tid]  = tid < 32 ? bl2[tid] : br2[tid - 32];
    }

    // ---- LN partial stats for left row ----
    {
        float s = 0.f, q = 0.f;
#pragma unroll
        for (int c = 0; c < 32; ++c) { s += xl[c]; q = fmaf(xl[c], xl[c], q); }
        pS[half*256 + px] = s;
        pQ[half*256 + px] = q;
    }

    // ---- stage X_left px-major bf16 swizzled ----
    uint4* X16 = (uint4*)(smem + XP_OFF);
#pragma unroll
    for (int cb = 0; cb < 4; ++cb) {
        uint4 u;
        u.x = f2bf(xl[cb*8+0]) | ((unsigned)f2bf(xl[cb*8+1]) << 16);
        u.y = f2bf(xl[cb*8+2]) | ((unsigned)f2bf(xl[cb*8+3]) << 16);
        u.z = f2bf(xl[cb*8+4]) | ((unsigned)f2bf(xl[cb*8+5]) << 16);
        u.w = f2bf(xl[cb*8+6]) | ((unsigned)f2bf(xl[cb*8+7]) << 16);
        X16[px*8 + ((half*4 + cb) ^ (px & 7))] = u;
    }
    __syncthreads();
    if (half == 0) {
        float s = pS[px] + pS[256 + px];
        float q = pQ[px] + pQ[256 + px];
        float mu = s * (1.f / 64.f);
        float var = q * (1.f / 64.f) - mu * mu;
        float rstd = rsqrtf(var + 1e-6f);
        aArr[px] = rstd;
        bbArr[px] = -rstd * mu;
    }
    __syncthreads();

    const uint4* W16 = (const uint4*)wpack;

    // proj one side (q always; v gated) over this wave's 2 px-tiles
    auto proj_side = [&](int wq, int wvv, unsigned char* qdst,
                         unsigned char* vdst, int chbase, bool ln, bool doV) {
        short8 bfr0[2], bfr1[2];
#pragma unroll
        for (int i = 0; i < 2; ++i) {
            int p = (wv*2 + i)*16 + lr;
            bfr0[i] = __builtin_bit_cast(short8, X16[p*8 + (g ^ (p&7))]);
            bfr1[i] = __builtin_bit_cast(short8, X16[p*8 + ((4+g) ^ (p&7))]);
        }
        // ---- q: D[ch][px] ----
#pragma unroll
        for (int ot = 0; ot < 4; ++ot) {
            const int out0 = ot * 16;
            short8 af0 = __builtin_bit_cast(short8, W16[wq + (out0+lr)*8 + g]);
            short8 af1 = __builtin_bit_cast(short8, W16[wq + (out0+lr)*8 + 4 + g]);
            const int ch0 = out0 + 4*g;
            f32x4 c1 = *(const f32x4*)&(ln ? sArr : bqrA)[ch0];
            f32x4 c2 = ln ? *(const f32x4*)&tArr[ch0] : (f32x4){0.f,0.f,0.f,0.f};
#pragma unroll
            for (int i = 0; i < 2; ++i) {
                f32x4 acc = {0.f,0.f,0.f,0.f};
                acc = mfma16(af0, bfr0[i], acc);
                acc = mfma16(af1, bfr1[i], acc);
                const int p = (wv*2+i)*16 + lr;
                float q0,q1,q2,q3;
                if (ln) {
                    const float a_ = aArr[p], b_ = bbArr[p];
                    q0 = fmaf(a_, acc[0], fmaf(b_, c1[0], c2[0]));
                    q1 = fmaf(a_, acc[1], fmaf(b_, c1[1], c2[1]));
                    q2 = fmaf(a_, acc[2], fmaf(b_, c1[2], c2[2]));
                    q3 = fmaf(a_, acc[3], fmaf(b_, c1[3], c2[3]));
                } else {
                    q0 = acc[0]+c1[0]; q1 = acc[1]+c1[1];
                    q2 = acc[2]+c1[2]; q3 = acc[3]+c1[3];
                }
                unsigned lo = f2bf(q0) | ((unsigned)f2bf(q1) << 16);
                unsigned hi = f2bf(q2) | ((unsigned)f2bf(q3) << 16);
                *(uint2*)(qdst + p*128 + (((ch0>>3) ^ (p&7))*16) + (ch0&7)*2)
                    = make_uint2(lo, hi);
            }
        }
        // ---- v: swapped operands -> D[px][ch], 8B store ----
        if (doV) {
#pragma unroll
            for (int ot = 0; ot < 2; ++ot) {
                const int out0 = ot * 16;
                short8 af0 = __builtin_bit_cast(short8, W16[wvv + (out0+lr)*8 + g]);
                short8 af1 = __builtin_bit_cast(short8, W16[wvv + (out0+lr)*8 + 4 + g]);
                const int ch = out0 + lr;
                const float bv = bvA[chbase + ch];
#pragma unroll
                for (int i = 0; i < 2; ++i) {
                    f32x4 acc = {0.f,0.f,0.f,0.f};
                    acc = mfma16(bfr0[i], af0, acc);
                    acc = mfma16(bfr1[i], af1, acc);
                    unsigned lo = f2bf(acc[0]+bv) | ((unsigned)f2bf(acc[1]+bv) << 16);
                    unsigned hi = f2bf(acc[2]+bv) | ((unsigned)f2bf(acc[3]+bv) << 16);
                    const int vb = (wv*2+i)*2 + (g>>1);
                    *(uint2*)(vdst + ch*512 + ((vb ^ (ch&7))*16) + (g&1)*8)
                        = make_uint2(lo, hi);
                }
            }
        }
    };

    // v_l (VL) feeds dir1 (gamma); v_r (VR) feeds dir0 (beta)
    proj_side(0, 1024, smem + QL_OFF, smem + VL_OFF, 0, true, needR);
    __syncthreads();

    // ---- stage X_right ----
#pragma unroll
    for (int cb = 0; cb < 4; ++cb) {
        uint4 u;
        u.x = f2bf(xr_[cb*8+0]) | ((unsigned)f2bf(xr_[cb*8+1]) << 16);
        u.y = f2bf(xr_[cb*8+2]) | ((unsigned)f2bf(xr_[cb*8+3]) << 16);
        u.z = f2bf(xr_[cb*8+4]) | ((unsigned)f2bf(xr_[cb*8+5]) << 16);
        u.w = f2bf(xr_[cb*8+6]) | ((unsigned)f2bf(xr_[cb*8+7]) << 16);
        X16[px*8 + ((half*4 + cb) ^ (px & 7))] = u;
    }
    __syncthreads();

    proj_side(512, 1280, smem + QR_OFF, smem + VR_OFF, 32, false, needL);
    __syncthreads();   // all q/v in LDS; X region becomes P

    // ------- attention: waves 0-3 dir0, waves 4-7 dir1; 4 chunks each -------
    const int dir = wv >> 2, wsub = wv & 3;
    if (dir ? needR : needL) {
        unsigned char* Pw = smem + XP_OFF + wv * 4096;
        const float cs = 0.125f * 1.44269504088896f;   // scale * log2(e)

        const uint4* Q16 = (const uint4*)(smem + (dir ? QR_OFF : QL_OFF));
        const uint4* K16 = (const uint4*)(smem + (dir ? QL_OFF : QR_OFF));
        const uint4* V16 = (const uint4*)(smem + (dir ? VL_OFF : VR_OFF));
        const float* coef = coefA + dir * 32;

        for (int c = 0; c < 4; ++c) {
            const int row0 = c * 64 + wsub * 16;
            const int qpx = row0 + lr;
            short8 qf0 = __builtin_bit_cast(short8, Q16[qpx*8 + (g ^ (qpx&7))]);
            short8 qf1 = __builtin_bit_cast(short8, Q16[qpx*8 + ((4+g) ^ (qpx&7))]);

            f32x4 sacc[16];
#pragma unroll
            for (int t = 0; t < 16; ++t) sacc[t] = (f32x4){0.f,0.f,0.f,0.f};
            __builtin_amdgcn_s_setprio(1);
#pragma unroll
            for (int t = 0; t < 16; ++t) {
                const int key = t * 16 + lr;
                const int sw = key & 7;
                short8 a0 = __builtin_bit_cast(short8, K16[key*8 + (g ^ sw)]);
                short8 a1 = __builtin_bit_cast(short8, K16[key*8 + ((4+g) ^ sw)]);
                sacc[t] = mfma16(a0, qf0, sacc[t]);
                sacc[t] = mfma16(a1, qf1, sacc[t]);
            }
            __builtin_amdgcn_s_setprio(0);
            float mx = -3.0e38f;
#pragma unroll
            for (int t = 0; t < 16; ++t)
                mx = fmaxf(mx, fmaxf(fmaxf(sacc[t][0], sacc[t][1]),
                                     fmaxf(sacc[t][2], sacc[t][3])));
            mx = fmaxf(mx, __shfl_xor(mx, 16));
            mx = fmaxf(mx, __shfl_xor(mx, 32));

            float lsum = 0.f;
            f32x4 o0 = (f32x4){0.f,0.f,0.f,0.f};
            f32x4 o1 = (f32x4){0.f,0.f,0.f,0.f};
#pragma unroll
            for (int hh = 0; hh < 2; ++hh) {
#pragma unroll
                for (int t8 = 0; t8 < 8; ++t8) {
                    const int t16 = hh * 8 + t8;
                    float p0 = exp2f((sacc[t16][0] - mx) * cs);
                    float p1 = exp2f((sacc[t16][1] - mx) * cs);
                    float p2 = exp2f((sacc[t16][2] - mx) * cs);
                    float p3 = exp2f((sacc[t16][3] - mx) * cs);
                    lsum += (p0 + p1) + (p2 + p3);
                    unsigned lo = f2bf(p0) | ((unsigned)f2bf(p1) << 16);
                    unsigned hi = f2bf(p2) | ((unsigned)f2bf(p3) << 16);
                    int pb = (2*t8 + (g >> 1)) ^ (lr & 7);
                    *(uint2*)(Pw + lr*256 + pb*16 + (g & 1)*8) = make_uint2(lo, hi);
                }
#pragma unroll
                for (int t = 0; t < 4; ++t) {
                    const int pb = 4*t + g;
                    const int vb = 16*hh + 4*t + g;
                    short8 pa = __builtin_bit_cast(short8,
                                *(const uint4*)(Pw + lr*256 + ((pb ^ (lr&7))*16)));
                    short8 v0 = __builtin_bit_cast(short8, V16[lr*32 + (vb ^ (lr&7))]);
                    short8 v1 = __builtin_bit_cast(short8, V16[(16+lr)*32 + (vb ^ (lr&7))]);
                    o0 = mfma16(pa, v0, o0);
                    o1 = mfma16(pa, v1, o1);
                }
            }
            lsum += __shfl_xor(lsum, 16);
            lsum += __shfl_xor(lsum, 32);
            const float inv = 1.f / lsum;

            float* Ot = (float*)Pw;
#pragma unroll
            for (int r = 0; r < 4; ++r) Ot[lr*17 + (g*4 + r)] = o0[r];
#pragma unroll
            for (int r = 0; r < 4; ++r) Ot[(16+lr)*17 + (g*4 + r)] = o1[r];

            float* outp = out + obase + (size_t)(dir*32) * HW + row0 + lr;
#pragma unroll
            for (int it = 0; it < 8; ++it) {
                const int ch = it*4 + g;
                outp[(size_t)ch * HW] += Ot[ch*17 + lr] * inv * coef[ch];
            }
        }
    }
}

extern "C" void kernel_launch(void* const* d_in, const int* in_sizes, int n_in,
                              void* d_out, int out_size, void* d_ws, size_t ws_size,
                              hipStream_t stream) {
    (void)in_sizes; (void)n_in; (void)out_size; (void)ws_size;
    const float* xr    = (const float*)d_in[0];
    const float* xh    = (const float*)d_in[1];
    const float* lnw   = (const float*)d_in[2];
    const float* lnb   = (const float*)d_in[3];
    const float* wl1   = (const float*)d_in[4];
    const float* bl1   = (const float*)d_in[5];
    const float* wr1   = (const float*)d_in[6];
    const float* br1   = (const float*)d_in[7];
    const float* wl2   = (const float*)d_in[8];
    const float* bl2   = (const float*)d_in[9];
    const float* wr2   = (const float*)d_in[10];
    const float* br2   = (const float*)d_in[11];
    const float* wlres = (const float*)d_in[12];
    const float* blres = (const float*)d_in[13];
    const float* wrres = (const float*)d_in[14];
    const float* brres = (const float*)d_in[15];
    const float* beta  = (const float*)d_in[16];
    const float* gamma = (const float*)d_in[17];
    float* out = (float*)d_out;

    __hip_bfloat16* wpack = (__hip_bfloat16*)d_ws;
    float* st = (float*)((unsigned char*)d_ws + 32768);

    res_kernel<<<dim3(1024, 2), dim3(256), 0, stream>>>(
        xr, xh, wlres, blres, wrres, brres, out);
    prep_kernel<<<dim3(4), dim3(64), 0, stream>>>(
        wl1, bl1, wr1, wl2, wr2, lnw, lnb, wpack, st);
    attn_kernel<<<dim3(1024), dim3(512), 0, stream>>>(
        xr, xh, wpack, st, br1, bl2, br2, beta, gamma, out);
}